// Round 10
// baseline (284.566 us; speedup 1.0000x reference)
//
#include <hip/hip_runtime.h>

// ---------------------------------------------------------------------------
// MultiHeadSelfAttention: B=4, L=2048, H=8, DK=DV=64, fp32 in/out.
// Reference quirks: logits *= sqrt(DK)=8 (multiply, not divide);
// ctx flattened dv-major (i = dv*H + h) before the final projection.
//
// v8: kv-split-4, 1024 blocks (4/CU), 32 waves/CU. Block = 512 thr = 8 waves
// = 2 qw (32 q-rows each) x 4 half (512 keys each). KVBLK=32, single 32KB
// LDS epoch buffer, __syncthreads-pair sync (spill/count-proof). Per-tile
// compute text verbatim r9 (PASS). 4-way flash-merge via LDS (f16 partial O).
// Ones-lsum-MFMA is BANNED (bisection: present in all NaN rounds 3-5).
// ---------------------------------------------------------------------------

typedef _Float16 half4v __attribute__((ext_vector_type(4)));
typedef _Float16 half8v __attribute__((ext_vector_type(8)));
typedef float    float4v __attribute__((ext_vector_type(4)));

#define BB   4
#define LL   2048
#define HH   8
#define DKV  64
#define NROW (BB * LL)            /* 8192 */
#define QSCALE 11.541560327111707f /* 8 * log2(e): folded into wq so the attn loop uses exp2 */

#define KVB  32                   /* keys per tile */
#define NEP  16                   /* epochs: 512 keys per half / 32 */

#define GLOAD_LDS(gp, sp) \
    __builtin_amdgcn_global_load_lds((const __attribute__((address_space(1))) void*)(gp), \
                                     (__attribute__((address_space(3))) void*)(sp), 16, 0, 0)

// ---------------- prep: x -> f16 ----------------
__global__ __launch_bounds__(256) void k_prep_x(const float* __restrict__ x,
                                                _Float16* __restrict__ xh) {
    int i = blockIdx.x * 256 + threadIdx.x;       // NROW*64/4 = 131072 threads
    float4v v = ((const float4v*)x)[i];
    half4v h;
    h[0] = (_Float16)v[0]; h[1] = (_Float16)v[1];
    h[2] = (_Float16)v[2]; h[3] = (_Float16)v[3];
    ((half4v*)xh)[i] = h;
}

// ---------------- prep: concat+transpose W (and bias) -> Wt[1536][64] f16 ----
__global__ __launch_bounds__(256) void k_prep_w(const float* __restrict__ wq, const float* __restrict__ bq,
                                                const float* __restrict__ wk, const float* __restrict__ bk,
                                                const float* __restrict__ wv, const float* __restrict__ bv,
                                                _Float16* __restrict__ wt, float* __restrict__ biasc) {
    int idx = blockIdx.x * 256 + threadIdx.x;     // 1536*64 = 98304
    int j = idx >> 6, i = idx & 63;
    const float* w; const float* bsrc; int jj; float sc = 1.0f;
    if (j < 512)       { w = wq; bsrc = bq; jj = j;        sc = QSCALE; }
    else if (j < 1024) { w = wk; bsrc = bk; jj = j - 512;  }
    else               { w = wv; bsrc = bv; jj = j - 1024; }
    wt[idx] = (_Float16)(w[i * 512 + jj] * sc);
    if (i == 0) biasc[j] = bsrc[jj] * sc;
}

// ---------------- prep: wo (dv-major rows) -> wo2t[64][512] f16, k = h*64+dv --
__global__ __launch_bounds__(256) void k_prep_wo(const float* __restrict__ wo,
                                                 _Float16* __restrict__ wo2t) {
    int idx = blockIdx.x * 256 + threadIdx.x;     // 64*512 = 32768
    int j = idx >> 9, k = idx & 511;
    int dv = k & 63, h = k >> 6;
    wo2t[idx] = (_Float16)wo[(dv * HH + h) * 64 + j];
}

// ---------------- QKV projection GEMM: [8192,64] @ [64,1536] ----------------
// V is written directly TRANSPOSED into vt[bh][dv][l].
__global__ __launch_bounds__(256) void k_proj(const _Float16* __restrict__ xh,
                                              const _Float16* __restrict__ wt,
                                              const float* __restrict__ biasc,
                                              _Float16* __restrict__ qh,
                                              _Float16* __restrict__ kh,
                                              _Float16* __restrict__ vtw) {
    int wid = threadIdx.x >> 6, lane = threadIdx.x & 63;
    int g = lane >> 4, c = lane & 15;
    int m0 = blockIdx.x * 64 + wid * 16;
    int n0 = blockIdx.y * 64;

    half8v a0 = *(const half8v*)(xh + (m0 + c) * 64 + g * 8);
    half8v a1 = *(const half8v*)(xh + (m0 + c) * 64 + 32 + g * 8);

    float4v acc[4] = {};
#pragma unroll
    for (int t = 0; t < 4; ++t) {
        const _Float16* wp = wt + (n0 + t * 16 + c) * 64 + g * 8;
        half8v b0 = *(const half8v*)(wp);
        half8v b1 = *(const half8v*)(wp + 32);
        acc[t] = __builtin_amdgcn_mfma_f32_16x16x32_f16(a0, b0, acc[t], 0, 0, 0);
        acc[t] = __builtin_amdgcn_mfma_f32_16x16x32_f16(a1, b1, acc[t], 0, 0, 0);
    }
#pragma unroll
    for (int t = 0; t < 4; ++t) {
        int j = n0 + t * 16 + c;
        float bias = biasc[j];
        int mat = j >> 9, jj = j & 511, h = jj >> 6;
        if (mat == 2) {
            int b = m0 >> 11, l0 = m0 & 2047;
            half4v hv;
#pragma unroll
            for (int r = 0; r < 4; ++r) hv[r] = (_Float16)(acc[t][r] + bias);
            *(half4v*)(vtw + ((size_t)(b * 8 + h) * 64 + t * 16 + c) * 2048 + l0 + g * 4) = hv;
        } else {
            int cc = (t * 16 + c);
            _Float16* dst = (mat == 0) ? qh : kh;
#pragma unroll
            for (int r = 0; r < 4; ++r) {
                int m = m0 + g * 4 + r;
                int b = m >> 11, l = m & 2047;
                dst[((size_t)(b * HH + h) * LL + l) * 64 + cc] = (_Float16)(acc[t][r] + bias);
            }
        }
    }
}

// ---------------- flash attention v8: kv-split-4, 32 q-rows/wave -------------
// LDS epoch buffer (32KB): [h=0: K 4K | V 4K][h=1]...[h=3]. K tile [32][128B]
// row-swizzled (row&7)<<4; V tile [64 dv][64B] slot-swizzled (dv&3)<<4.
// Waves 0-3 stage K (4 x 1KB chunks, one per half), waves 4-7 stage V.
__global__ __launch_bounds__(512, 8) void k_attn(const _Float16* __restrict__ qh,
                                                 const _Float16* __restrict__ kh,
                                                 const _Float16* __restrict__ vt,
                                                 _Float16* __restrict__ ctx) {
    __shared__ char lds[32768];

    int tid = threadIdx.x;
    int wid = tid >> 6, lane = tid & 63;
    int g = lane >> 4, c = lane & 15;
    int qw = wid & 1, half = wid >> 1;            // 2 q-groups x 4 kv-quarters

    // 1024 blocks: xcd = bid%8 -> 4 heads per XCD (K+V = 2MB, L2-resident)
    int bid = blockIdx.x;
    int xcd = bid & 7;
    int rest = bid >> 3;                  // 0..127
    int bh = xcd * 4 + (rest >> 5);       // 0..31
    int qc = rest & 31;                   // 32 chunks of 64 q-rows
    int q0 = qc * 64 + qw * 32;

    const _Float16* qp = qh + ((size_t)bh * LL + q0) * 64;
    const char* kg = (const char*)(kh + (size_t)bh * LL * 64);   // [L][128B]
    const char* vg = (const char*)(vt + (size_t)bh * 64 * LL);   // [dv=64][4096B]

    half8v qa0 = *(const half8v*)(qp + c * 64 + g * 8);
    half8v qa1 = *(const half8v*)(qp + c * 64 + 32 + g * 8);
    half8v qb0 = *(const half8v*)(qp + (16 + c) * 64 + g * 8);
    half8v qb1 = *(const half8v*)(qp + (16 + c) * 64 + 32 + g * 8);

    // ---- staging geometry: wave w stages chunk ci = wid + 8j (j = half index)
    // ci*1024 is the linear LDS dest (= h*8192 + type*4096 + sub*1024).
    int kvw = wid >> 2;                           // 0 = K-stager, 1 = V-stager
    int sub = wid & 3;
    int pS = sub * 1024 + lane * 16;
    int rK = pS >> 7,  cK = pS & 127;             // K tile row/col
    int rV = pS >> 6,  cV = pS & 63;              // V tile row/col
    int baseK = rK * 128 + (cK ^ ((rK & 7) << 4));               // + j*65536 + e*4096
    int baseV = rV * 4096 + (cV ^ ((rV & 3) << 4));              // + j*1024  + e*64

#define STAGE(e) do {                                                         \
        if (kvw == 0) {                                                       \
            const char* s0 = kg + baseK + (size_t)(e) * 4096;                 \
            _Pragma("unroll") for (int j = 0; j < 4; ++j)                     \
                GLOAD_LDS(s0 + j * 65536, lds + (wid + 8 * j) * 1024);        \
        } else {                                                              \
            const char* s0 = vg + baseV + (size_t)(e) * 64;                   \
            _Pragma("unroll") for (int j = 0; j < 4; ++j)                     \
                GLOAD_LDS(s0 + j * 1024, lds + (wid + 8 * j) * 1024);         \
        }                                                                     \
    } while (0)

    float4v oa[4] = {}, ob[4] = {};
    float ma = -1e30f, lsumA = 0.0f;
    float mb = -1e30f, lsumB = 0.0f;

    STAGE(0);

    const char* lk = lds + half * 8192;
    const char* lv = lk + 4096;

    for (int e = 0; e < NEP; ++e) {
        __syncthreads();   // all waves' stage loads for epoch e have landed

#pragma unroll
        for (int s = 0; s < 2; ++s) {
            int krow = s * 16 + c;
            int swzk = (krow & 7) << 4;
            half8v kf0 = *(const half8v*)(lk + krow * 128 + ((g * 16) ^ swzk));
            half8v kf1 = *(const half8v*)(lk + krow * 128 + ((g * 16 + 64) ^ swzk));

            float4v sva = {};
            sva = __builtin_amdgcn_mfma_f32_16x16x32_f16(kf0, qa0, sva, 0, 0, 0);
            sva = __builtin_amdgcn_mfma_f32_16x16x32_f16(kf1, qa1, sva, 0, 0, 0);
            float4v svb = {};
            svb = __builtin_amdgcn_mfma_f32_16x16x32_f16(kf0, qb0, svb, 0, 0, 0);
            svb = __builtin_amdgcn_mfma_f32_16x16x32_f16(kf1, qb1, svb, 0, 0, 0);

            // ---- softmax set A (r9 algebra; max3-nested reduce) ----
            float pmaxa = fmaxf(fmaxf(fmaxf(sva[0], sva[1]), sva[2]), sva[3]);
            pmaxa = fmaxf(pmaxa, __shfl_xor(pmaxa, 16));
            pmaxa = fmaxf(pmaxa, __shfl_xor(pmaxa, 32));
            if (__any(pmaxa > ma + 3.0f)) {          // deferred rescale (T13)
                float mn = fmaxf(ma, pmaxa);
                float sc = __builtin_amdgcn_exp2f(ma - mn);
                lsumA *= sc;
#pragma unroll
                for (int t = 0; t < 4; ++t) oa[t] *= sc;
                ma = mn;
            }
            float pa0 = __builtin_amdgcn_exp2f(sva[0] - ma);
            float pa1 = __builtin_amdgcn_exp2f(sva[1] - ma);
            float pa2 = __builtin_amdgcn_exp2f(sva[2] - ma);
            float pa3 = __builtin_amdgcn_exp2f(sva[3] - ma);
            lsumA += (pa0 + pa1) + (pa2 + pa3);
            half4v pha;
            pha[0] = (_Float16)pa0; pha[1] = (_Float16)pa1;
            pha[2] = (_Float16)pa2; pha[3] = (_Float16)pa3;

            // ---- softmax set B ----
            float pmaxb = fmaxf(fmaxf(fmaxf(svb[0], svb[1]), svb[2]), svb[3]);
            pmaxb = fmaxf(pmaxb, __shfl_xor(pmaxb, 16));
            pmaxb = fmaxf(pmaxb, __shfl_xor(pmaxb, 32));
            if (__any(pmaxb > mb + 3.0f)) {
                float mn = fmaxf(mb, pmaxb);
                float sc = __builtin_amdgcn_exp2f(mb - mn);
                lsumB *= sc;
#pragma unroll
                for (int t = 0; t < 4; ++t) ob[t] *= sc;
                mb = mn;
            }
            float pb0 = __builtin_amdgcn_exp2f(svb[0] - mb);
            float pb1 = __builtin_amdgcn_exp2f(svb[1] - mb);
            float pb2 = __builtin_amdgcn_exp2f(svb[2] - mb);
            float pb3 = __builtin_amdgcn_exp2f(svb[3] - mb);
            lsumB += (pb0 + pb1) + (pb2 + pb3);
            half4v phb;
            phb[0] = (_Float16)pb0; phb[1] = (_Float16)pb1;
            phb[2] = (_Float16)pb2; phb[3] = (_Float16)pb3;

            int vcol = (s * 32 + g * 8) ^ ((c & 3) << 4);
#pragma unroll
            for (int t = 0; t < 4; ++t) {
                half4v vf = *(const half4v*)(lv + (t * 16 + c) * 64 + vcol);
                oa[t] = __builtin_amdgcn_mfma_f32_16x16x16f16(vf, pha, oa[t], 0, 0, 0);
                ob[t] = __builtin_amdgcn_mfma_f32_16x16x16f16(vf, phb, ob[t], 0, 0, 0);
            }
        }

        if (e + 1 < NEP) {
            __syncthreads();   // all reads of this epoch done -> safe to overwrite
            STAGE(e + 1);
        }
    }
#undef STAGE

    // ---- 4-way kv flash-merge via LDS (f16 partial O; m,l in f32) -----------
    __syncthreads();
    if (half != 0) {
        char* mr = ((char*)lds) + (((half - 1) * 2 + qw) * 64 + lane) * 80;
#pragma unroll
        for (int t = 0; t < 4; ++t) {
            half4v ha, hb;
#pragma unroll
            for (int r = 0; r < 4; ++r) { ha[r] = (_Float16)oa[t][r]; hb[r] = (_Float16)ob[t][r]; }
            *(half4v*)(mr + t * 8) = ha;
            *(half4v*)(mr + 32 + t * 8) = hb;
        }
        float4v sc;
        sc[0] = ma; sc[1] = lsumA; sc[2] = mb; sc[3] = lsumB;
        *(float4v*)(mr + 64) = sc;
    }
    __syncthreads();
    if (half == 0) {
#pragma unroll
        for (int j = 1; j <= 3; ++j) {
            const char* mr = ((const char*)lds) + (((j - 1) * 2 + qw) * 64 + lane) * 80;
            float4v sc = *(const float4v*)(mr + 64);
            float mNA = fmaxf(ma, sc[0]);
            float s1a = __builtin_amdgcn_exp2f(ma - mNA);
            float s2a = __builtin_amdgcn_exp2f(sc[0] - mNA);
            float mNB = fmaxf(mb, sc[2]);
            float s1b = __builtin_amdgcn_exp2f(mb - mNB);
            float s2b = __builtin_amdgcn_exp2f(sc[2] - mNB);
#pragma unroll
            for (int t = 0; t < 4; ++t) {
                half4v ha = *(const half4v*)(mr + t * 8);
                half4v hb = *(const half4v*)(mr + 32 + t * 8);
#pragma unroll
                for (int r = 0; r < 4; ++r) {
                    oa[t][r] = oa[t][r] * s1a + (float)ha[r] * s2a;
                    ob[t][r] = ob[t][r] * s1b + (float)hb[r] * s2b;
                }
            }
            lsumA = lsumA * s1a + sc[1] * s2a;
            lsumB = lsumB * s1b + sc[3] * s2b;
            ma = mNA; mb = mNB;
        }

        lsumA += __shfl_xor(lsumA, 16);
        lsumA += __shfl_xor(lsumA, 32);
        lsumB += __shfl_xor(lsumB, 16);
        lsumB += __shfl_xor(lsumB, 32);
        float inva = 1.0f / lsumA;
        float invb = 1.0f / lsumB;

        _Float16* cpa = ctx + ((size_t)bh * LL + q0 + c) * 64 + g * 4;
        _Float16* cpb = cpa + 16 * 64;
#pragma unroll
        for (int t = 0; t < 4; ++t) {
            half4v hva, hvb;
#pragma unroll
            for (int r = 0; r < 4; ++r) {
                hva[r] = (_Float16)(oa[t][r] * inva);
                hvb[r] = (_Float16)(ob[t][r] * invb);
            }
            *(half4v*)(cpa + t * 16) = hva;
            *(half4v*)(cpb + t * 16) = hvb;
        }
    }
}

// ---------------- output projection: [8192,512] @ [512,64] ----------------
__global__ __launch_bounds__(64) void k_oproj(const _Float16* __restrict__ ctx,
                                              const _Float16* __restrict__ wo2t,
                                              const float* __restrict__ bo,
                                              float* __restrict__ out) {
    int lane = threadIdx.x & 63;
    int g = lane >> 4, c = lane & 15;
    int m0 = blockIdx.x * 16;
    int b = m0 >> 11, l = m0 & 2047;
    const _Float16* cbase = ctx + ((size_t)b * HH * LL + l) * 64;

    float4v acc[4] = {};
#pragma unroll
    for (int kc = 0; kc < 16; ++kc) {
        int hh = kc >> 1;
        const _Float16* ap = cbase + (size_t)hh * LL * 64 + c * 64 + (kc & 1) * 32 + g * 8;
        half8v a = *(const half8v*)(ap);
#pragma unroll
        for (int t = 0; t < 4; ++t) {
            half8v bf = *(const half8v*)(wo2t + (t * 16 + c) * 512 + kc * 32 + g * 8);
            acc[t] = __builtin_amdgcn_mfma_f32_16x16x32_f16(a, bf, acc[t], 0, 0, 0);
        }
    }
#pragma unroll
    for (int t = 0; t < 4; ++t) {
        float bias = bo[t * 16 + c];
#pragma unroll
        for (int r = 0; r < 4; ++r) {
            int mm = m0 + g * 4 + r;
            out[mm * 64 + t * 16 + c] = acc[t][r] + bias;
        }
    }
}

// ---------------------------------------------------------------------------
extern "C" void kernel_launch(void* const* d_in, const int* in_sizes, int n_in,
                              void* d_out, int out_size, void* d_ws, size_t ws_size,
                              hipStream_t stream) {
    const float* x  = (const float*)d_in[0];
    const float* wq = (const float*)d_in[1];
    const float* bq = (const float*)d_in[2];
    const float* wk = (const float*)d_in[3];
    const float* bk = (const float*)d_in[4];
    const float* wv = (const float*)d_in[5];
    const float* bv = (const float*)d_in[6];
    const float* wo = (const float*)d_in[7];
    const float* bo = (const float*)d_in[8];
    float* out = (float*)d_out;

    char* ws = (char*)d_ws;
    _Float16* xh    = (_Float16*)(ws);                       // 1 MB
    _Float16* wt    = (_Float16*)(ws + 1048576);             // 192 KB
    float*    biasc = (float*)   (ws + 1245184);             // 6 KB
    _Float16* wo2t  = (_Float16*)(ws + 1251328);             // 64 KB
    _Float16* qh    = (_Float16*)(ws + 1316864);             // 8 MB
    _Float16* kh    = (_Float16*)(ws + 1316864 + 1ull * 8388608);
    _Float16* vt    = (_Float16*)(ws + 1316864 + 2ull * 8388608);
    _Float16* ctx   = (_Float16*)(ws + 1316864 + 3ull * 8388608);

    hipLaunchKernelGGL(k_prep_x,  dim3(512),      dim3(256), 0, stream, x, xh);
    hipLaunchKernelGGL(k_prep_w,  dim3(384),      dim3(256), 0, stream, wq, bq, wk, bk, wv, bv, wt, biasc);
    hipLaunchKernelGGL(k_prep_wo, dim3(128),      dim3(256), 0, stream, wo, wo2t);
    hipLaunchKernelGGL(k_proj,    dim3(128, 24),  dim3(256), 0, stream, xh, wt, biasc, qh, kh, vt);
    hipLaunchKernelGGL(k_attn,    dim3(1024),     dim3(512), 0, stream, qh, kh, vt, ctx);
    hipLaunchKernelGGL(k_oproj,   dim3(512),      dim3(64),  0, stream, ctx, wo2t, bo, out);
}

// Round 12
// 110.721 us; speedup vs baseline: 2.5701x; 2.5701x over previous
//
#include <hip/hip_runtime.h>

// ---------------------------------------------------------------------------
// MultiHeadSelfAttention: B=4, L=2048, H=8, DK=DV=64, fp32 in/out.
// Reference quirks: logits *= sqrt(DK)=8 (multiply, not divide);
// ctx flattened dv-major (i = dv*H + h) before the final projection.
//
// v10 = v9 with ONE change: all k_attn barriers are explicit
//   asm "s_waitcnt vmcnt(0) [lgkmcnt(0)]; s_barrier"  (memory clobber)
// instead of __syncthreads(). Session evidence: every pass (r2/r7/r9) used
// explicit counted vmcnt + s_barrier; every unexplained failure (v5 NaN,
// v9 stale-data) trusted __syncthreads to drain global_load_lds (v8 "passed"
// only under spill traffic that masked the race). Theory: __syncthreads does
// not reliably emit the vmcnt(0) drain for in-flight global_load_lds.
// Ones-lsum-MFMA remains BANNED.
// ---------------------------------------------------------------------------

typedef _Float16 half4v __attribute__((ext_vector_type(4)));
typedef _Float16 half8v __attribute__((ext_vector_type(8)));
typedef float    float4v __attribute__((ext_vector_type(4)));

#define BB   4
#define LL   2048
#define HH   8
#define DKV  64
#define NROW (BB * LL)            /* 8192 */
#define QSCALE 11.541560327111707f /* 8 * log2(e): folded into wq so the attn loop uses exp2 */

#define KVBLK 64
#define NEP   16                  /* epochs: 1024 keys per half / 64 */

#define GLOAD_LDS(gp, sp) \
    __builtin_amdgcn_global_load_lds((const __attribute__((address_space(1))) void*)(gp), \
                                     (__attribute__((address_space(3))) void*)(sp), 16, 0, 0)

// Explicit barrier class (proven r2/r7/r9): drain BOTH counters, then barrier.
#define SYNC_FULL do {                                                        \
        asm volatile("s_waitcnt vmcnt(0) lgkmcnt(0)" ::: "memory");           \
        asm volatile("s_barrier" ::: "memory");                               \
    } while (0)

// ---------------- prep: x -> f16 ----------------
__global__ __launch_bounds__(256) void k_prep_x(const float* __restrict__ x,
                                                _Float16* __restrict__ xh) {
    int i = blockIdx.x * 256 + threadIdx.x;       // NROW*64/4 = 131072 threads
    float4v v = ((const float4v*)x)[i];
    half4v h;
    h[0] = (_Float16)v[0]; h[1] = (_Float16)v[1];
    h[2] = (_Float16)v[2]; h[3] = (_Float16)v[3];
    ((half4v*)xh)[i] = h;
}

// ---------------- prep: concat+transpose W (and bias) -> Wt[1536][64] f16 ----
__global__ __launch_bounds__(256) void k_prep_w(const float* __restrict__ wq, const float* __restrict__ bq,
                                                const float* __restrict__ wk, const float* __restrict__ bk,
                                                const float* __restrict__ wv, const float* __restrict__ bv,
                                                _Float16* __restrict__ wt, float* __restrict__ biasc) {
    int idx = blockIdx.x * 256 + threadIdx.x;     // 1536*64 = 98304
    int j = idx >> 6, i = idx & 63;
    const float* w; const float* bsrc; int jj; float sc = 1.0f;
    if (j < 512)       { w = wq; bsrc = bq; jj = j;        sc = QSCALE; }
    else if (j < 1024) { w = wk; bsrc = bk; jj = j - 512;  }
    else               { w = wv; bsrc = bv; jj = j - 1024; }
    wt[idx] = (_Float16)(w[i * 512 + jj] * sc);
    if (i == 0) biasc[j] = bsrc[jj] * sc;
}

// ---------------- prep: wo (dv-major rows) -> wo2t[64][512] f16, k = h*64+dv --
__global__ __launch_bounds__(256) void k_prep_wo(const float* __restrict__ wo,
                                                 _Float16* __restrict__ wo2t) {
    int idx = blockIdx.x * 256 + threadIdx.x;     // 64*512 = 32768
    int j = idx >> 9, k = idx & 511;
    int dv = k & 63, h = k >> 6;
    wo2t[idx] = (_Float16)wo[(dv * HH + h) * 64 + j];
}

// ---------------- QKV projection GEMM: [8192,64] @ [64,1536] ----------------
// V is written directly TRANSPOSED into vt[bh][dv][l].
__global__ __launch_bounds__(256) void k_proj(const _Float16* __restrict__ xh,
                                              const _Float16* __restrict__ wt,
                                              const float* __restrict__ biasc,
                                              _Float16* __restrict__ qh,
                                              _Float16* __restrict__ kh,
                                              _Float16* __restrict__ vtw) {
    int wid = threadIdx.x >> 6, lane = threadIdx.x & 63;
    int g = lane >> 4, c = lane & 15;
    int m0 = blockIdx.x * 64 + wid * 16;
    int n0 = blockIdx.y * 64;

    half8v a0 = *(const half8v*)(xh + (m0 + c) * 64 + g * 8);
    half8v a1 = *(const half8v*)(xh + (m0 + c) * 64 + 32 + g * 8);

    float4v acc[4] = {};
#pragma unroll
    for (int t = 0; t < 4; ++t) {
        const _Float16* wp = wt + (n0 + t * 16 + c) * 64 + g * 8;
        half8v b0 = *(const half8v*)(wp);
        half8v b1 = *(const half8v*)(wp + 32);
        acc[t] = __builtin_amdgcn_mfma_f32_16x16x32_f16(a0, b0, acc[t], 0, 0, 0);
        acc[t] = __builtin_amdgcn_mfma_f32_16x16x32_f16(a1, b1, acc[t], 0, 0, 0);
    }
#pragma unroll
    for (int t = 0; t < 4; ++t) {
        int j = n0 + t * 16 + c;
        float bias = biasc[j];
        int mat = j >> 9, jj = j & 511, h = jj >> 6;
        if (mat == 2) {
            int b = m0 >> 11, l0 = m0 & 2047;
            half4v hv;
#pragma unroll
            for (int r = 0; r < 4; ++r) hv[r] = (_Float16)(acc[t][r] + bias);
            *(half4v*)(vtw + ((size_t)(b * 8 + h) * 64 + t * 16 + c) * 2048 + l0 + g * 4) = hv;
        } else {
            int cc = (t * 16 + c);
            _Float16* dst = (mat == 0) ? qh : kh;
#pragma unroll
            for (int r = 0; r < 4; ++r) {
                int m = m0 + g * 4 + r;
                int b = m >> 11, l = m & 2047;
                dst[((size_t)(b * HH + h) * LL + l) * 64 + cc] = (_Float16)(acc[t][r] + bias);
            }
        }
    }
}

// ---------------- flash attention v10: 16 q-rows/wave, kv-split-2 ------------
// Block = 512 thr = 4 qw x 2 half; 64 q-rows/block; 1024 blocks (4/CU,
// 32 waves/CU). LDS 32KB single buffer [K0 8K | V0 8K | K1 8K | V1 8K];
// wave w stages linear chunk [w*4096, w*4096+4096) as 4x1KB gloads with
// pre-swizzled source (rule 21). Sync = explicit asm drains (see SYNC_FULL).
// Epilogue: 2-way flash-merge via LDS (f16 partial O, 12KB).
__global__ __launch_bounds__(512, 4) void k_attn(const _Float16* __restrict__ qh,
                                                 const _Float16* __restrict__ kh,
                                                 const _Float16* __restrict__ vt,
                                                 _Float16* __restrict__ ctx) {
    __shared__ char lds[32768];

    int tid = threadIdx.x;
    int wid = tid >> 6, lane = tid & 63;
    int g = lane >> 4, c = lane & 15;
    int qw = wid & 3, half = wid >> 2;    // 4 q-groups x 2 kv-halves

    // 1024 blocks: xcd = bid%8 -> 4 heads per XCD (K+V = 2MB, L2-resident)
    int bid = blockIdx.x;
    int xcd = bid & 7;
    int rest = bid >> 3;                  // 0..127
    int bh = xcd * 4 + (rest >> 5);       // 0..31
    int qc = rest & 31;                   // 32 chunks of 64 q-rows
    int q0 = qc * 64 + qw * 16;

    const _Float16* qp = qh + ((size_t)bh * LL + q0) * 64;
    const char* kg = (const char*)(kh + (size_t)bh * LL * 64);   // [L][128B]
    const char* vg = (const char*)(vt + (size_t)bh * 64 * LL);   // [dv=64][4096B]

    half8v qf0 = *(const half8v*)(qp + c * 64 + g * 8);
    half8v qf1 = *(const half8v*)(qp + c * 64 + 32 + g * 8);

    // ---- staging: wave w -> LDS [w*4096, w*4096+4096). Regions: K(h)=h*16384,
    // V(h)=h*16384+8192. w0,1=K0; w2,3=V0; w4,5=K1; w6,7=V1.
    int isV = (wid >> 1) & 1, hs = wid >> 2, sub = wid & 1;
    const char* sbase[4];
    int estride;
    if (!isV) {
        estride = KVBLK * 128;            // 8192 B per epoch (64 keys)
#pragma unroll
        for (int j = 0; j < 4; ++j) {
            int p = sub * 4096 + j * 1024 + lane * 16;   // offset in 8KB K tile
            int row = p >> 7, col = p & 127;
            sbase[j] = kg + (size_t)hs * 131072 + row * 128 + (col ^ ((row & 7) << 4));
        }
    } else {
        estride = KVBLK * 2;              // 128 B per epoch per dv row
#pragma unroll
        for (int j = 0; j < 4; ++j) {
            int p = sub * 4096 + j * 1024 + lane * 16;   // offset in 8KB V tile
            int dv = p >> 7, kb = p & 127;
            sbase[j] = vg + (size_t)dv * 4096 + hs * 2048 + (kb ^ ((dv & 7) << 4));
        }
    }

#define STAGE(e) do {                                                         \
        _Pragma("unroll") for (int j = 0; j < 4; ++j)                         \
            GLOAD_LDS(sbase[j] + (size_t)(e) * estride, lds + wid * 4096 + j * 1024); \
    } while (0)

    float4v o[4] = {};
    float m = -1e30f, lsum = 0.0f;
    int swzk_c = (c & 7) << 4;

    STAGE(0);

    const char* lk = lds + half * 16384;
    const char* lv = lk + 8192;

    for (int e = 0; e < NEP; ++e) {
        SYNC_FULL;   // vmcnt(0): this wave's stage loads landed; barrier: all
                     // waves'. lgkmcnt(0) folded in (free).

#pragma unroll
        for (int s = 0; s < 4; ++s) {
            int krow = s * 16 + c;
            int swzk = (krow & 7) << 4;
            half8v kf0 = *(const half8v*)(lk + krow * 128 + ((g * 16) ^ swzk));
            half8v kf1 = *(const half8v*)(lk + krow * 128 + ((g * 16 + 64) ^ swzk));
            float4v sv = {};
            sv = __builtin_amdgcn_mfma_f32_16x16x32_f16(kf0, qf0, sv, 0, 0, 0);
            sv = __builtin_amdgcn_mfma_f32_16x16x32_f16(kf1, qf1, sv, 0, 0, 0);

            // per-lane pmax; cross-lane reduce deferred into rare rescale branch
            float pmax = fmaxf(fmaxf(sv[0], sv[1]), fmaxf(sv[2], sv[3]));
            if (__any(pmax > m + 3.0f)) {
                pmax = fmaxf(pmax, __shfl_xor(pmax, 16));
                pmax = fmaxf(pmax, __shfl_xor(pmax, 32));
                float mn = fmaxf(m, pmax);
                float sc = __builtin_amdgcn_exp2f(m - mn);
                lsum *= sc;
#pragma unroll
                for (int t = 0; t < 4; ++t) o[t] *= sc;
                m = mn;
            }

            float p0 = __builtin_amdgcn_exp2f(sv[0] - m);
            float p1 = __builtin_amdgcn_exp2f(sv[1] - m);
            float p2 = __builtin_amdgcn_exp2f(sv[2] - m);
            float p3 = __builtin_amdgcn_exp2f(sv[3] - m);
            lsum += (p0 + p1) + (p2 + p3);
            half4v ph;
            ph[0] = (_Float16)p0; ph[1] = (_Float16)p1;
            ph[2] = (_Float16)p2; ph[3] = (_Float16)p3;

            int vcol = (s * 32 + g * 8) ^ swzk_c;
#pragma unroll
            for (int t = 0; t < 4; ++t) {
                half4v vf = *(const half4v*)(lv + (t * 16 + c) * 128 + vcol);
                o[t] = __builtin_amdgcn_mfma_f32_16x16x16f16(vf, ph, o[t], 0, 0, 0);
            }
        }

        if (e + 1 < NEP) {
            SYNC_FULL;   // lgkmcnt(0): all waves' reads of epoch e complete
                         // before overwrite (vmcnt already 0 -> free).
            STAGE(e + 1);
        }
    }
#undef STAGE

    // ---- 2-way kv flash-merge via LDS (f16 partial O; 256 x 48B = 12KB) -----
    SYNC_FULL;
    if (half == 1) {
        char* mr = lds + (qw * 64 + lane) * 48;
#pragma unroll
        for (int t = 0; t < 4; ++t) {
            half4v hv;
#pragma unroll
            for (int r = 0; r < 4; ++r) hv[r] = (_Float16)o[t][r];
            *(half4v*)(mr + t * 8) = hv;
        }
        *(float*)(mr + 32) = m;
        *(float*)(mr + 36) = lsum;
    }
    SYNC_FULL;
    if (half == 0) {
        const char* mr = lds + (qw * 64 + lane) * 48;
        float m2 = *(const float*)(mr + 32);
        float l2 = *(const float*)(mr + 36);
        float mN = fmaxf(m, m2);
        float s1 = __builtin_amdgcn_exp2f(m - mN);
        float s2 = __builtin_amdgcn_exp2f(m2 - mN);
#pragma unroll
        for (int t = 0; t < 4; ++t) {
            half4v h2 = *(const half4v*)(mr + t * 8);
#pragma unroll
            for (int r = 0; r < 4; ++r)
                o[t][r] = o[t][r] * s1 + (float)h2[r] * s2;
        }
        lsum = lsum * s1 + l2 * s2;

        lsum += __shfl_xor(lsum, 16);
        lsum += __shfl_xor(lsum, 32);
        float inv = 1.0f / lsum;

        _Float16* cp = ctx + ((size_t)bh * LL + q0 + c) * 64 + g * 4;
#pragma unroll
        for (int t = 0; t < 4; ++t) {
            half4v hv;
#pragma unroll
            for (int r = 0; r < 4; ++r) hv[r] = (_Float16)(o[t][r] * inv);
            *(half4v*)(cp + t * 16) = hv;
        }
    }
}

// ---------------- output projection: [8192,512] @ [512,64] ----------------
__global__ __launch_bounds__(64) void k_oproj(const _Float16* __restrict__ ctx,
                                              const _Float16* __restrict__ wo2t,
                                              const float* __restrict__ bo,
                                              float* __restrict__ out) {
    int lane = threadIdx.x & 63;
    int g = lane >> 4, c = lane & 15;
    int m0 = blockIdx.x * 16;
    int b = m0 >> 11, l = m0 & 2047;
    const _Float16* cbase = ctx + ((size_t)b * HH * LL + l) * 64;

    float4v acc[4] = {};
#pragma unroll
    for (int kc = 0; kc < 16; ++kc) {
        int hh = kc >> 1;
        const _Float16* ap = cbase + (size_t)hh * LL * 64 + c * 64 + (kc & 1) * 32 + g * 8;
        half8v a = *(const half8v*)(ap);
#pragma unroll
        for (int t = 0; t < 4; ++t) {
            half8v bf = *(const half8v*)(wo2t + (t * 16 + c) * 512 + kc * 32 + g * 8);
            acc[t] = __builtin_amdgcn_mfma_f32_16x16x32_f16(a, bf, acc[t], 0, 0, 0);
        }
    }
#pragma unroll
    for (int t = 0; t < 4; ++t) {
        float bias = bo[t * 16 + c];
#pragma unroll
        for (int r = 0; r < 4; ++r) {
            int mm = m0 + g * 4 + r;
            out[mm * 64 + t * 16 + c] = acc[t][r] + bias;
        }
    }
}

// ---------------------------------------------------------------------------
extern "C" void kernel_launch(void* const* d_in, const int* in_sizes, int n_in,
                              void* d_out, int out_size, void* d_ws, size_t ws_size,
                              hipStream_t stream) {
    const float* x  = (const float*)d_in[0];
    const float* wq = (const float*)d_in[1];
    const float* bq = (const float*)d_in[2];
    const float* wk = (const float*)d_in[3];
    const float* bk = (const float*)d_in[4];
    const float* wv = (const float*)d_in[5];
    const float* bv = (const float*)d_in[6];
    const float* wo = (const float*)d_in[7];
    const float* bo = (const float*)d_in[8];
    float* out = (float*)d_out;

    char* ws = (char*)d_ws;
    _Float16* xh    = (_Float16*)(ws);                       // 1 MB
    _Float16* wt    = (_Float16*)(ws + 1048576);             // 192 KB
    float*    biasc = (float*)   (ws + 1245184);             // 6 KB
    _Float16* wo2t  = (_Float16*)(ws + 1251328);             // 64 KB
    _Float16* qh    = (_Float16*)(ws + 1316864);             // 8 MB
    _Float16* kh    = (_Float16*)(ws + 1316864 + 1ull * 8388608);
    _Float16* vt    = (_Float16*)(ws + 1316864 + 2ull * 8388608);
    _Float16* ctx   = (_Float16*)(ws + 1316864 + 3ull * 8388608);

    hipLaunchKernelGGL(k_prep_x,  dim3(512),      dim3(256), 0, stream, x, xh);
    hipLaunchKernelGGL(k_prep_w,  dim3(384),      dim3(256), 0, stream, wq, bq, wk, bk, wv, bv, wt, biasc);
    hipLaunchKernelGGL(k_prep_wo, dim3(128),      dim3(256), 0, stream, wo, wo2t);
    hipLaunchKernelGGL(k_proj,    dim3(128, 24),  dim3(256), 0, stream, xh, wt, biasc, qh, kh, vt);
    hipLaunchKernelGGL(k_attn,    dim3(1024),     dim3(512), 0, stream, qh, kh, vt, ctx);
    hipLaunchKernelGGL(k_oproj,   dim3(512),      dim3(64),  0, stream, ctx, wo2t, bo, out);
}

// Round 13
// 106.107 us; speedup vs baseline: 2.6819x; 1.0435x over previous
//
#include <hip/hip_runtime.h>

// ---------------------------------------------------------------------------
// MultiHeadSelfAttention: B=4, L=2048, H=8, DK=DV=64, fp32 in/out.
// Reference quirks: logits *= sqrt(DK)=8 (multiply, not divide);
// ctx flattened dv-major (i = dv*H + h) before the final projection.
//
// v11 = r9 (best: attn 73.9us) + low-risk shavings:
//  - skip-shfl steady-state softmax (r12-proven; identical rescale condition)
//  - k_oproj 4-wave blocks (weight-panel reuse)
//  - merged prep_w/prep_wo dispatch
// SESSION RULES: barriers guarding global_load_lds must be explicit
// "s_waitcnt vmcnt(N) [lgkmcnt(0)]; s_barrier" asm (__syncthreads does NOT
// drain global_load_lds -> v5/v9 failures). Ones-lsum-MFMA stays banned.
// ---------------------------------------------------------------------------

typedef _Float16 half4v __attribute__((ext_vector_type(4)));
typedef _Float16 half8v __attribute__((ext_vector_type(8)));
typedef float    float4v __attribute__((ext_vector_type(4)));

#define BB   4
#define LL   2048
#define HH   8
#define DKV  64
#define NROW (BB * LL)            /* 8192 */
#define QSCALE 11.541560327111707f /* 8 * log2(e): folded into wq so the attn loop uses exp2 */

#define KVBLK 64
#define NEP   16                  /* epochs; each stages 2 tiles (one per kv-half) */

#define GLOAD_LDS(gp, sp) \
    __builtin_amdgcn_global_load_lds((const __attribute__((address_space(1))) void*)(gp), \
                                     (__attribute__((address_space(3))) void*)(sp), 16, 0, 0)

// ---------------- prep: x -> f16 ----------------
__global__ __launch_bounds__(256) void k_prep_x(const float* __restrict__ x,
                                                _Float16* __restrict__ xh) {
    int i = blockIdx.x * 256 + threadIdx.x;       // NROW*64/4 = 131072 threads
    float4v v = ((const float4v*)x)[i];
    half4v h;
    h[0] = (_Float16)v[0]; h[1] = (_Float16)v[1];
    h[2] = (_Float16)v[2]; h[3] = (_Float16)v[3];
    ((half4v*)xh)[i] = h;
}

// ------- prep (merged): Wt[1536][64] + bias  AND  wo2t[64][512] ------------
__global__ __launch_bounds__(256) void k_prep_w(const float* __restrict__ wq, const float* __restrict__ bq,
                                                const float* __restrict__ wk, const float* __restrict__ bk,
                                                const float* __restrict__ wv, const float* __restrict__ bv,
                                                const float* __restrict__ wo,
                                                _Float16* __restrict__ wt, float* __restrict__ biasc,
                                                _Float16* __restrict__ wo2t) {
    int bidx = blockIdx.x;
    if (bidx < 384) {
        int idx = bidx * 256 + threadIdx.x;       // 1536*64 = 98304
        int j = idx >> 6, i = idx & 63;
        const float* w; const float* bsrc; int jj; float sc = 1.0f;
        if (j < 512)       { w = wq; bsrc = bq; jj = j;        sc = QSCALE; }
        else if (j < 1024) { w = wk; bsrc = bk; jj = j - 512;  }
        else               { w = wv; bsrc = bv; jj = j - 1024; }
        wt[idx] = (_Float16)(w[i * 512 + jj] * sc);
        if (i == 0) biasc[j] = bsrc[jj] * sc;
    } else {
        int idx = (bidx - 384) * 256 + threadIdx.x;   // 64*512 = 32768
        int j = idx >> 9, k = idx & 511;
        int dv = k & 63, h = k >> 6;
        wo2t[idx] = (_Float16)wo[(dv * HH + h) * 64 + j];
    }
}

// ---------------- QKV projection GEMM: [8192,64] @ [64,1536] ----------------
// V is written directly TRANSPOSED into vt[bh][dv][l].
__global__ __launch_bounds__(256) void k_proj(const _Float16* __restrict__ xh,
                                              const _Float16* __restrict__ wt,
                                              const float* __restrict__ biasc,
                                              _Float16* __restrict__ qh,
                                              _Float16* __restrict__ kh,
                                              _Float16* __restrict__ vtw) {
    int wid = threadIdx.x >> 6, lane = threadIdx.x & 63;
    int g = lane >> 4, c = lane & 15;
    int m0 = blockIdx.x * 64 + wid * 16;
    int n0 = blockIdx.y * 64;

    half8v a0 = *(const half8v*)(xh + (m0 + c) * 64 + g * 8);
    half8v a1 = *(const half8v*)(xh + (m0 + c) * 64 + 32 + g * 8);

    float4v acc[4] = {};
#pragma unroll
    for (int t = 0; t < 4; ++t) {
        const _Float16* wp = wt + (n0 + t * 16 + c) * 64 + g * 8;
        half8v b0 = *(const half8v*)(wp);
        half8v b1 = *(const half8v*)(wp + 32);
        acc[t] = __builtin_amdgcn_mfma_f32_16x16x32_f16(a0, b0, acc[t], 0, 0, 0);
        acc[t] = __builtin_amdgcn_mfma_f32_16x16x32_f16(a1, b1, acc[t], 0, 0, 0);
    }
#pragma unroll
    for (int t = 0; t < 4; ++t) {
        int j = n0 + t * 16 + c;
        float bias = biasc[j];
        int mat = j >> 9, jj = j & 511, h = jj >> 6;
        if (mat == 2) {
            int b = m0 >> 11, l0 = m0 & 2047;
            half4v hv;
#pragma unroll
            for (int r = 0; r < 4; ++r) hv[r] = (_Float16)(acc[t][r] + bias);
            *(half4v*)(vtw + ((size_t)(b * 8 + h) * 64 + t * 16 + c) * 2048 + l0 + g * 4) = hv;
        } else {
            int cc = (t * 16 + c);
            _Float16* dst = (mat == 0) ? qh : kh;
#pragma unroll
            for (int r = 0; r < 4; ++r) {
                int m = m0 + g * 4 + r;
                int b = m >> 11, l = m & 2047;
                dst[((size_t)(b * HH + h) * LL + l) * 64 + cc] = (_Float16)(acc[t][r] + bias);
            }
        }
    }
}

// ---------------- flash attention v11: kv-split-2, 32 q-rows/wave ------------
// (= r9's proven kernel + skip-shfl steady-state softmax)
__global__ __launch_bounds__(512, 4) void k_attn(const _Float16* __restrict__ qh,
                                                 const _Float16* __restrict__ kh,
                                                 const _Float16* __restrict__ vt,
                                                 _Float16* __restrict__ ctx) {
    // epoch buffer: [K0 8K][V0 8K][K1 8K][V1 8K] x2 double-buffer = 64KB
    __shared__ char lds[2 * 32768];

    int tid = threadIdx.x;
    int wid = tid >> 6, lane = tid & 63;
    int g = lane >> 4, c = lane & 15;
    int qw = wid & 3, half = wid >> 2;

    // 512 blocks: xcd = bid%8 -> 4 heads per XCD (K+V = 2MB, L2-resident)
    int bid = blockIdx.x;
    int xcd = bid & 7;
    int rest = bid >> 3;                  // 0..63
    int bh = xcd * 4 + (rest >> 4);       // 0..31
    int qc = rest & 15;                   // 16 chunks of 128 q-rows
    int q0 = qc * 128 + qw * 32;

    const _Float16* qp = qh + ((size_t)bh * LL + q0) * 64;
    const char* kg = (const char*)(kh + (size_t)bh * LL * 64);   // [L][64]: 8KB per KVBLK
    const char* vg = (const char*)(vt + (size_t)bh * 64 * LL);   // [dv=64][L]

    half8v qa0 = *(const half8v*)(qp + c * 64 + g * 8);
    half8v qa1 = *(const half8v*)(qp + c * 64 + 32 + g * 8);
    half8v qb0 = *(const half8v*)(qp + (16 + c) * 64 + g * 8);
    half8v qb1 = *(const half8v*)(qp + (16 + c) * 64 + 32 + g * 8);

    // ---- staging geometry (verbatim r9): 8 waves x 1KB per tile
    int pK   = wid * 1024 + lane * 16;            // byte offset in 8KB tile
    int rowS = pK >> 7;                           // tile row (128B rows)
    int srcK = (pK & ~127) | ((pK & 127) ^ ((rowS & 7) << 4));   // pre-swizzled source
    size_t srcV = (size_t)rowS * (LL * 2) + (size_t)((pK & 127) ^ ((rowS & 7) << 4));
    int pDst = wid * 1024;                        // HW adds lane*16

    // epoch e stages tile e (half0) and tile 16+e (half1)
#define STAGE(buf, e) do {                                                    \
        char* base = lds + (buf) * 32768;                                     \
        GLOAD_LDS(kg + (size_t)(e) * 8192 + srcK,        base + pDst);        \
        GLOAD_LDS(vg + srcV + (size_t)(e) * 128,         base + 8192 + pDst); \
        GLOAD_LDS(kg + (size_t)(16 + (e)) * 8192 + srcK, base + 16384 + pDst);\
        GLOAD_LDS(vg + srcV + (size_t)(16 + (e)) * 128,  base + 24576 + pDst);\
    } while (0)

    float4v oa[4] = {}, ob[4] = {};
    float ma = -1e30f, lsumA = 0.0f;
    float mb = -1e30f, lsumB = 0.0f;
    int swzk_c = (c & 7) << 4;

    STAGE(0, 0);

    for (int e = 0; e < NEP; ++e) {
        int cur = e & 1;
        if (e + 1 < NEP) {
            STAGE(cur ^ 1, e + 1);
            asm volatile("s_waitcnt vmcnt(4)" ::: "memory");
        } else {
            asm volatile("s_waitcnt vmcnt(0)" ::: "memory");
        }
        asm volatile("s_barrier" ::: "memory");

        const char* lk = lds + cur * 32768 + half * 16384;
        const char* lv = lk + 8192;

#pragma unroll
        for (int s = 0; s < 4; ++s) {
            int krow = s * 16 + c;
            int swzk = (krow & 7) << 4;
            half8v kf0 = *(const half8v*)(lk + krow * 128 + ((g * 16) ^ swzk));
            half8v kf1 = *(const half8v*)(lk + krow * 128 + ((g * 16 + 64) ^ swzk));

            float4v sva = {};
            sva = __builtin_amdgcn_mfma_f32_16x16x32_f16(kf0, qa0, sva, 0, 0, 0);
            sva = __builtin_amdgcn_mfma_f32_16x16x32_f16(kf1, qa1, sva, 0, 0, 0);
            float4v svb = {};
            svb = __builtin_amdgcn_mfma_f32_16x16x32_f16(kf0, qb0, svb, 0, 0, 0);
            svb = __builtin_amdgcn_mfma_f32_16x16x32_f16(kf1, qb1, svb, 0, 0, 0);

            // ---- softmax set A (skip-shfl steady state, r12-proven) ----
            float pmaxa = fmaxf(fmaxf(sva[0], sva[1]), fmaxf(sva[2], sva[3]));
            if (__any(pmaxa > ma + 3.0f)) {          // deferred rescale (T13)
                pmaxa = fmaxf(pmaxa, __shfl_xor(pmaxa, 16));
                pmaxa = fmaxf(pmaxa, __shfl_xor(pmaxa, 32));
                float mn = fmaxf(ma, pmaxa);
                float sc = __builtin_amdgcn_exp2f(ma - mn);
                lsumA *= sc;
#pragma unroll
                for (int t = 0; t < 4; ++t) oa[t] *= sc;
                ma = mn;
            }
            float pa0 = __builtin_amdgcn_exp2f(sva[0] - ma);
            float pa1 = __builtin_amdgcn_exp2f(sva[1] - ma);
            float pa2 = __builtin_amdgcn_exp2f(sva[2] - ma);
            float pa3 = __builtin_amdgcn_exp2f(sva[3] - ma);
            lsumA += (pa0 + pa1) + (pa2 + pa3);
            half4v pha;
            pha[0] = (_Float16)pa0; pha[1] = (_Float16)pa1;
            pha[2] = (_Float16)pa2; pha[3] = (_Float16)pa3;

            // ---- softmax set B ----
            float pmaxb = fmaxf(fmaxf(svb[0], svb[1]), fmaxf(svb[2], svb[3]));
            if (__any(pmaxb > mb + 3.0f)) {
                pmaxb = fmaxf(pmaxb, __shfl_xor(pmaxb, 16));
                pmaxb = fmaxf(pmaxb, __shfl_xor(pmaxb, 32));
                float mn = fmaxf(mb, pmaxb);
                float sc = __builtin_amdgcn_exp2f(mb - mn);
                lsumB *= sc;
#pragma unroll
                for (int t = 0; t < 4; ++t) ob[t] *= sc;
                mb = mn;
            }
            float pb0 = __builtin_amdgcn_exp2f(svb[0] - mb);
            float pb1 = __builtin_amdgcn_exp2f(svb[1] - mb);
            float pb2 = __builtin_amdgcn_exp2f(svb[2] - mb);
            float pb3 = __builtin_amdgcn_exp2f(svb[3] - mb);
            lsumB += (pb0 + pb1) + (pb2 + pb3);
            half4v phb;
            phb[0] = (_Float16)pb0; phb[1] = (_Float16)pb1;
            phb[2] = (_Float16)pb2; phb[3] = (_Float16)pb3;

            int vcol = (s * 32 + g * 8) ^ swzk_c;
#pragma unroll
            for (int t = 0; t < 4; ++t) {
                half4v vf = *(const half4v*)(lv + (t * 16 + c) * 128 + vcol);
                oa[t] = __builtin_amdgcn_mfma_f32_16x16x16f16(vf, pha, oa[t], 0, 0, 0);
                ob[t] = __builtin_amdgcn_mfma_f32_16x16x16f16(vf, phb, ob[t], 0, 0, 0);
            }
        }

        asm volatile("s_barrier" ::: "memory");
    }
#undef STAGE

    // ---- flash-merge of the two kv-halves via LDS (verbatim r9; no
    // global_load_lds in flight here, __syncthreads is safe) -----------------
    __syncthreads();
    if (half == 1) {
        float* mr = (float*)(lds + qw * 9216 + lane * 144);
#pragma unroll
        for (int t = 0; t < 4; ++t) *(float4v*)(mr + 4 * t) = oa[t];
#pragma unroll
        for (int t = 0; t < 4; ++t) *(float4v*)(mr + 16 + 4 * t) = ob[t];
        float4v sc; sc[0] = ma; sc[1] = lsumA; sc[2] = mb; sc[3] = lsumB;
        *(float4v*)(mr + 32) = sc;
    }
    __syncthreads();
    if (half == 0) {
        const float* mr = (const float*)(lds + qw * 9216 + lane * 144);
        float4v sc = *(const float4v*)(mr + 32);
        float ma2 = sc[0], la2 = sc[1], mb2 = sc[2], lb2 = sc[3];

        float mMA = fmaxf(ma, ma2);
        float s1a = __builtin_amdgcn_exp2f(ma - mMA);
        float s2a = __builtin_amdgcn_exp2f(ma2 - mMA);
        float mMB = fmaxf(mb, mb2);
        float s1b = __builtin_amdgcn_exp2f(mb - mMB);
        float s2b = __builtin_amdgcn_exp2f(mb2 - mMB);
#pragma unroll
        for (int t = 0; t < 4; ++t) {
            float4v o2 = *(const float4v*)(mr + 4 * t);
            oa[t] = oa[t] * s1a + o2 * s2a;
        }
#pragma unroll
        for (int t = 0; t < 4; ++t) {
            float4v o2 = *(const float4v*)(mr + 16 + 4 * t);
            ob[t] = ob[t] * s1b + o2 * s2b;
        }
        lsumA = lsumA * s1a + la2 * s2a;
        lsumB = lsumB * s1b + lb2 * s2b;

        lsumA += __shfl_xor(lsumA, 16);
        lsumA += __shfl_xor(lsumA, 32);
        lsumB += __shfl_xor(lsumB, 16);
        lsumB += __shfl_xor(lsumB, 32);
        float inva = 1.0f / lsumA;
        float invb = 1.0f / lsumB;

        _Float16* cpa = ctx + ((size_t)bh * LL + q0 + c) * 64 + g * 4;
        _Float16* cpb = cpa + 16 * 64;
#pragma unroll
        for (int t = 0; t < 4; ++t) {
            half4v hva, hvb;
#pragma unroll
            for (int r = 0; r < 4; ++r) {
                hva[r] = (_Float16)(oa[t][r] * inva);
                hvb[r] = (_Float16)(ob[t][r] * invb);
            }
            *(half4v*)(cpa + t * 16) = hva;
            *(half4v*)(cpb + t * 16) = hvb;
        }
    }
}

// ---------------- output projection: [8192,512] @ [512,64] ----------------
// 4-wave blocks (128 x 256): 4x fewer weight-panel re-reads than 512 x 64.
__global__ __launch_bounds__(256) void k_oproj(const _Float16* __restrict__ ctx,
                                               const _Float16* __restrict__ wo2t,
                                               const float* __restrict__ bo,
                                               float* __restrict__ out) {
    int wid = threadIdx.x >> 6, lane = threadIdx.x & 63;
    int g = lane >> 4, c = lane & 15;
    int m0 = blockIdx.x * 64 + wid * 16;
    int b = m0 >> 11, l = m0 & 2047;
    const _Float16* cbase = ctx + ((size_t)b * HH * LL + l) * 64;

    float4v acc[4] = {};
#pragma unroll
    for (int kc = 0; kc < 16; ++kc) {
        int hh = kc >> 1;
        const _Float16* ap = cbase + (size_t)hh * LL * 64 + c * 64 + (kc & 1) * 32 + g * 8;
        half8v a = *(const half8v*)(ap);
#pragma unroll
        for (int t = 0; t < 4; ++t) {
            half8v bf = *(const half8v*)(wo2t + (t * 16 + c) * 512 + kc * 32 + g * 8);
            acc[t] = __builtin_amdgcn_mfma_f32_16x16x32_f16(a, bf, acc[t], 0, 0, 0);
        }
    }
#pragma unroll
    for (int t = 0; t < 4; ++t) {
        float bias = bo[t * 16 + c];
#pragma unroll
        for (int r = 0; r < 4; ++r) {
            int mm = m0 + g * 4 + r;
            out[mm * 64 + t * 16 + c] = acc[t][r] + bias;
        }
    }
}

// ---------------------------------------------------------------------------
extern "C" void kernel_launch(void* const* d_in, const int* in_sizes, int n_in,
                              void* d_out, int out_size, void* d_ws, size_t ws_size,
                              hipStream_t stream) {
    const float* x  = (const float*)d_in[0];
    const float* wq = (const float*)d_in[1];
    const float* bq = (const float*)d_in[2];
    const float* wk = (const float*)d_in[3];
    const float* bk = (const float*)d_in[4];
    const float* wv = (const float*)d_in[5];
    const float* bv = (const float*)d_in[6];
    const float* wo = (const float*)d_in[7];
    const float* bo = (const float*)d_in[8];
    float* out = (float*)d_out;

    char* ws = (char*)d_ws;
    _Float16* xh    = (_Float16*)(ws);                       // 1 MB
    _Float16* wt    = (_Float16*)(ws + 1048576);             // 192 KB
    float*    biasc = (float*)   (ws + 1245184);             // 6 KB
    _Float16* wo2t  = (_Float16*)(ws + 1251328);             // 64 KB
    _Float16* qh    = (_Float16*)(ws + 1316864);             // 8 MB
    _Float16* kh    = (_Float16*)(ws + 1316864 + 1ull * 8388608);
    _Float16* vt    = (_Float16*)(ws + 1316864 + 2ull * 8388608);
    _Float16* ctx   = (_Float16*)(ws + 1316864 + 3ull * 8388608);

    hipLaunchKernelGGL(k_prep_x,  dim3(512),      dim3(256), 0, stream, x, xh);
    hipLaunchKernelGGL(k_prep_w,  dim3(512),      dim3(256), 0, stream,
                       wq, bq, wk, bk, wv, bv, wo, wt, biasc, wo2t);
    hipLaunchKernelGGL(k_proj,    dim3(128, 24),  dim3(256), 0, stream, xh, wt, biasc, qh, kh, vt);
    hipLaunchKernelGGL(k_attn,    dim3(512),      dim3(512), 0, stream, qh, kh, vt, ctx);
    hipLaunchKernelGGL(k_oproj,   dim3(128),      dim3(256), 0, stream, ctx, wo2t, bo, out);
}

// Round 14
// 99.014 us; speedup vs baseline: 2.8740x; 1.0716x over previous
//
#include <hip/hip_runtime.h>

// ---------------------------------------------------------------------------
// MultiHeadSelfAttention: B=4, L=2048, H=8, DK=DV=64, fp32 in/out.
// Reference quirks: logits *= sqrt(DK)=8 (multiply, not divide);
// ctx flattened dv-major (i = dv*H + h) before the final projection.
//
// v12 = r13 attn (best: 70.6us, PASS) + non-attn fixes:
//  - k_oproj reverted to r9-proven 512 blocks x 64 thr (128x256 was 0.5
//    block/CU -> latency-bound regression, -3.5us)
//  - single merged prep dispatch (x->f16, Wt+bias, wo2t): one less launch
// SESSION RULES: barriers guarding global_load_lds must be explicit
// "s_waitcnt vmcnt(N); s_barrier" asm (__syncthreads does NOT drain
// global_load_lds -> v5/v9 failures). Ones-lsum-MFMA stays banned.
// ---------------------------------------------------------------------------

typedef _Float16 half4v __attribute__((ext_vector_type(4)));
typedef _Float16 half8v __attribute__((ext_vector_type(8)));
typedef float    float4v __attribute__((ext_vector_type(4)));

#define BB   4
#define LL   2048
#define HH   8
#define DKV  64
#define NROW (BB * LL)            /* 8192 */
#define QSCALE 11.541560327111707f /* 8 * log2(e): folded into wq so the attn loop uses exp2 */

#define KVBLK 64
#define NEP   16                  /* epochs; each stages 2 tiles (one per kv-half) */

#define GLOAD_LDS(gp, sp) \
    __builtin_amdgcn_global_load_lds((const __attribute__((address_space(1))) void*)(gp), \
                                     (__attribute__((address_space(3))) void*)(sp), 16, 0, 0)

// ------- prep (merged): x->f16 ; Wt[1536][64]+bias ; wo2t[64][512] ----------
__global__ __launch_bounds__(256) void k_prep(const float* __restrict__ x,
                                              const float* __restrict__ wq, const float* __restrict__ bq,
                                              const float* __restrict__ wk, const float* __restrict__ bk,
                                              const float* __restrict__ wv, const float* __restrict__ bv,
                                              const float* __restrict__ wo,
                                              _Float16* __restrict__ xh,
                                              _Float16* __restrict__ wt, float* __restrict__ biasc,
                                              _Float16* __restrict__ wo2t) {
    int bidx = blockIdx.x;
    if (bidx < 512) {
        int i = bidx * 256 + threadIdx.x;             // NROW*64/4 = 131072
        float4v v = ((const float4v*)x)[i];
        half4v h;
        h[0] = (_Float16)v[0]; h[1] = (_Float16)v[1];
        h[2] = (_Float16)v[2]; h[3] = (_Float16)v[3];
        ((half4v*)xh)[i] = h;
    } else if (bidx < 896) {
        int idx = (bidx - 512) * 256 + threadIdx.x;   // 1536*64 = 98304
        int j = idx >> 6, i = idx & 63;
        const float* w; const float* bsrc; int jj; float sc = 1.0f;
        if (j < 512)       { w = wq; bsrc = bq; jj = j;        sc = QSCALE; }
        else if (j < 1024) { w = wk; bsrc = bk; jj = j - 512;  }
        else               { w = wv; bsrc = bv; jj = j - 1024; }
        wt[idx] = (_Float16)(w[i * 512 + jj] * sc);
        if (i == 0) biasc[j] = bsrc[jj] * sc;
    } else {
        int idx = (bidx - 896) * 256 + threadIdx.x;   // 64*512 = 32768
        int j = idx >> 9, k = idx & 511;
        int dv = k & 63, h = k >> 6;
        wo2t[idx] = (_Float16)wo[(dv * HH + h) * 64 + j];
    }
}

// ---------------- QKV projection GEMM: [8192,64] @ [64,1536] ----------------
// V is written directly TRANSPOSED into vt[bh][dv][l].
__global__ __launch_bounds__(256) void k_proj(const _Float16* __restrict__ xh,
                                              const _Float16* __restrict__ wt,
                                              const float* __restrict__ biasc,
                                              _Float16* __restrict__ qh,
                                              _Float16* __restrict__ kh,
                                              _Float16* __restrict__ vtw) {
    int wid = threadIdx.x >> 6, lane = threadIdx.x & 63;
    int g = lane >> 4, c = lane & 15;
    int m0 = blockIdx.x * 64 + wid * 16;
    int n0 = blockIdx.y * 64;

    half8v a0 = *(const half8v*)(xh + (m0 + c) * 64 + g * 8);
    half8v a1 = *(const half8v*)(xh + (m0 + c) * 64 + 32 + g * 8);

    float4v acc[4] = {};
#pragma unroll
    for (int t = 0; t < 4; ++t) {
        const _Float16* wp = wt + (n0 + t * 16 + c) * 64 + g * 8;
        half8v b0 = *(const half8v*)(wp);
        half8v b1 = *(const half8v*)(wp + 32);
        acc[t] = __builtin_amdgcn_mfma_f32_16x16x32_f16(a0, b0, acc[t], 0, 0, 0);
        acc[t] = __builtin_amdgcn_mfma_f32_16x16x32_f16(a1, b1, acc[t], 0, 0, 0);
    }
#pragma unroll
    for (int t = 0; t < 4; ++t) {
        int j = n0 + t * 16 + c;
        float bias = biasc[j];
        int mat = j >> 9, jj = j & 511, h = jj >> 6;
        if (mat == 2) {
            int b = m0 >> 11, l0 = m0 & 2047;
            half4v hv;
#pragma unroll
            for (int r = 0; r < 4; ++r) hv[r] = (_Float16)(acc[t][r] + bias);
            *(half4v*)(vtw + ((size_t)(b * 8 + h) * 64 + t * 16 + c) * 2048 + l0 + g * 4) = hv;
        } else {
            int cc = (t * 16 + c);
            _Float16* dst = (mat == 0) ? qh : kh;
#pragma unroll
            for (int r = 0; r < 4; ++r) {
                int m = m0 + g * 4 + r;
                int b = m >> 11, l = m & 2047;
                dst[((size_t)(b * HH + h) * LL + l) * 64 + cc] = (_Float16)(acc[t][r] + bias);
            }
        }
    }
}

// ---------------- flash attention v12 (= r13, byte-identical) ----------------
__global__ __launch_bounds__(512, 4) void k_attn(const _Float16* __restrict__ qh,
                                                 const _Float16* __restrict__ kh,
                                                 const _Float16* __restrict__ vt,
                                                 _Float16* __restrict__ ctx) {
    // epoch buffer: [K0 8K][V0 8K][K1 8K][V1 8K] x2 double-buffer = 64KB
    __shared__ char lds[2 * 32768];

    int tid = threadIdx.x;
    int wid = tid >> 6, lane = tid & 63;
    int g = lane >> 4, c = lane & 15;
    int qw = wid & 3, half = wid >> 2;

    // 512 blocks: xcd = bid%8 -> 4 heads per XCD (K+V = 2MB, L2-resident)
    int bid = blockIdx.x;
    int xcd = bid & 7;
    int rest = bid >> 3;                  // 0..63
    int bh = xcd * 4 + (rest >> 4);       // 0..31
    int qc = rest & 15;                   // 16 chunks of 128 q-rows
    int q0 = qc * 128 + qw * 32;

    const _Float16* qp = qh + ((size_t)bh * LL + q0) * 64;
    const char* kg = (const char*)(kh + (size_t)bh * LL * 64);   // [L][64]: 8KB per KVBLK
    const char* vg = (const char*)(vt + (size_t)bh * 64 * LL);   // [dv=64][L]

    half8v qa0 = *(const half8v*)(qp + c * 64 + g * 8);
    half8v qa1 = *(const half8v*)(qp + c * 64 + 32 + g * 8);
    half8v qb0 = *(const half8v*)(qp + (16 + c) * 64 + g * 8);
    half8v qb1 = *(const half8v*)(qp + (16 + c) * 64 + 32 + g * 8);

    // ---- staging geometry (verbatim r9): 8 waves x 1KB per tile
    int pK   = wid * 1024 + lane * 16;            // byte offset in 8KB tile
    int rowS = pK >> 7;                           // tile row (128B rows)
    int srcK = (pK & ~127) | ((pK & 127) ^ ((rowS & 7) << 4));   // pre-swizzled source
    size_t srcV = (size_t)rowS * (LL * 2) + (size_t)((pK & 127) ^ ((rowS & 7) << 4));
    int pDst = wid * 1024;                        // HW adds lane*16

    // epoch e stages tile e (half0) and tile 16+e (half1)
#define STAGE(buf, e) do {                                                    \
        char* base = lds + (buf) * 32768;                                     \
        GLOAD_LDS(kg + (size_t)(e) * 8192 + srcK,        base + pDst);        \
        GLOAD_LDS(vg + srcV + (size_t)(e) * 128,         base + 8192 + pDst); \
        GLOAD_LDS(kg + (size_t)(16 + (e)) * 8192 + srcK, base + 16384 + pDst);\
        GLOAD_LDS(vg + srcV + (size_t)(16 + (e)) * 128,  base + 24576 + pDst);\
    } while (0)

    float4v oa[4] = {}, ob[4] = {};
    float ma = -1e30f, lsumA = 0.0f;
    float mb = -1e30f, lsumB = 0.0f;
    int swzk_c = (c & 7) << 4;

    STAGE(0, 0);

    for (int e = 0; e < NEP; ++e) {
        int cur = e & 1;
        if (e + 1 < NEP) {
            STAGE(cur ^ 1, e + 1);
            asm volatile("s_waitcnt vmcnt(4)" ::: "memory");
        } else {
            asm volatile("s_waitcnt vmcnt(0)" ::: "memory");
        }
        asm volatile("s_barrier" ::: "memory");

        const char* lk = lds + cur * 32768 + half * 16384;
        const char* lv = lk + 8192;

#pragma unroll
        for (int s = 0; s < 4; ++s) {
            int krow = s * 16 + c;
            int swzk = (krow & 7) << 4;
            half8v kf0 = *(const half8v*)(lk + krow * 128 + ((g * 16) ^ swzk));
            half8v kf1 = *(const half8v*)(lk + krow * 128 + ((g * 16 + 64) ^ swzk));

            float4v sva = {};
            sva = __builtin_amdgcn_mfma_f32_16x16x32_f16(kf0, qa0, sva, 0, 0, 0);
            sva = __builtin_amdgcn_mfma_f32_16x16x32_f16(kf1, qa1, sva, 0, 0, 0);
            float4v svb = {};
            svb = __builtin_amdgcn_mfma_f32_16x16x32_f16(kf0, qb0, svb, 0, 0, 0);
            svb = __builtin_amdgcn_mfma_f32_16x16x32_f16(kf1, qb1, svb, 0, 0, 0);

            // ---- softmax set A (skip-shfl steady state, r12-proven) ----
            float pmaxa = fmaxf(fmaxf(sva[0], sva[1]), fmaxf(sva[2], sva[3]));
            if (__any(pmaxa > ma + 3.0f)) {          // deferred rescale (T13)
                pmaxa = fmaxf(pmaxa, __shfl_xor(pmaxa, 16));
                pmaxa = fmaxf(pmaxa, __shfl_xor(pmaxa, 32));
                float mn = fmaxf(ma, pmaxa);
                float sc = __builtin_amdgcn_exp2f(ma - mn);
                lsumA *= sc;
#pragma unroll
                for (int t = 0; t < 4; ++t) oa[t] *= sc;
                ma = mn;
            }
            float pa0 = __builtin_amdgcn_exp2f(sva[0] - ma);
            float pa1 = __builtin_amdgcn_exp2f(sva[1] - ma);
            float pa2 = __builtin_amdgcn_exp2f(sva[2] - ma);
            float pa3 = __builtin_amdgcn_exp2f(sva[3] - ma);
            lsumA += (pa0 + pa1) + (pa2 + pa3);
            half4v pha;
            pha[0] = (_Float16)pa0; pha[1] = (_Float16)pa1;
            pha[2] = (_Float16)pa2; pha[3] = (_Float16)pa3;

            // ---- softmax set B ----
            float pmaxb = fmaxf(fmaxf(svb[0], svb[1]), fmaxf(svb[2], svb[3]));
            if (__any(pmaxb > mb + 3.0f)) {
                pmaxb = fmaxf(pmaxb, __shfl_xor(pmaxb, 16));
                pmaxb = fmaxf(pmaxb, __shfl_xor(pmaxb, 32));
                float mn = fmaxf(mb, pmaxb);
                float sc = __builtin_amdgcn_exp2f(mb - mn);
                lsumB *= sc;
#pragma unroll
                for (int t = 0; t < 4; ++t) ob[t] *= sc;
                mb = mn;
            }
            float pb0 = __builtin_amdgcn_exp2f(svb[0] - mb);
            float pb1 = __builtin_amdgcn_exp2f(svb[1] - mb);
            float pb2 = __builtin_amdgcn_exp2f(svb[2] - mb);
            float pb3 = __builtin_amdgcn_exp2f(svb[3] - mb);
            lsumB += (pb0 + pb1) + (pb2 + pb3);
            half4v phb;
            phb[0] = (_Float16)pb0; phb[1] = (_Float16)pb1;
            phb[2] = (_Float16)pb2; phb[3] = (_Float16)pb3;

            int vcol = (s * 32 + g * 8) ^ swzk_c;
#pragma unroll
            for (int t = 0; t < 4; ++t) {
                half4v vf = *(const half4v*)(lv + (t * 16 + c) * 128 + vcol);
                oa[t] = __builtin_amdgcn_mfma_f32_16x16x16f16(vf, pha, oa[t], 0, 0, 0);
                ob[t] = __builtin_amdgcn_mfma_f32_16x16x16f16(vf, phb, ob[t], 0, 0, 0);
            }
        }

        asm volatile("s_barrier" ::: "memory");
    }
#undef STAGE

    // ---- flash-merge of the two kv-halves via LDS (no global_load_lds in
    // flight here -> __syncthreads safe) --------------------------------------
    __syncthreads();
    if (half == 1) {
        float* mr = (float*)(lds + qw * 9216 + lane * 144);
#pragma unroll
        for (int t = 0; t < 4; ++t) *(float4v*)(mr + 4 * t) = oa[t];
#pragma unroll
        for (int t = 0; t < 4; ++t) *(float4v*)(mr + 16 + 4 * t) = ob[t];
        float4v sc; sc[0] = ma; sc[1] = lsumA; sc[2] = mb; sc[3] = lsumB;
        *(float4v*)(mr + 32) = sc;
    }
    __syncthreads();
    if (half == 0) {
        const float* mr = (const float*)(lds + qw * 9216 + lane * 144);
        float4v sc = *(const float4v*)(mr + 32);
        float ma2 = sc[0], la2 = sc[1], mb2 = sc[2], lb2 = sc[3];

        float mMA = fmaxf(ma, ma2);
        float s1a = __builtin_amdgcn_exp2f(ma - mMA);
        float s2a = __builtin_amdgcn_exp2f(ma2 - mMA);
        float mMB = fmaxf(mb, mb2);
        float s1b = __builtin_amdgcn_exp2f(mb - mMB);
        float s2b = __builtin_amdgcn_exp2f(mb2 - mMB);
#pragma unroll
        for (int t = 0; t < 4; ++t) {
            float4v o2 = *(const float4v*)(mr + 4 * t);
            oa[t] = oa[t] * s1a + o2 * s2a;
        }
#pragma unroll
        for (int t = 0; t < 4; ++t) {
            float4v o2 = *(const float4v*)(mr + 16 + 4 * t);
            ob[t] = ob[t] * s1b + o2 * s2b;
        }
        lsumA = lsumA * s1a + la2 * s2a;
        lsumB = lsumB * s1b + lb2 * s2b;

        lsumA += __shfl_xor(lsumA, 16);
        lsumA += __shfl_xor(lsumA, 32);
        lsumB += __shfl_xor(lsumB, 16);
        lsumB += __shfl_xor(lsumB, 32);
        float inva = 1.0f / lsumA;
        float invb = 1.0f / lsumB;

        _Float16* cpa = ctx + ((size_t)bh * LL + q0 + c) * 64 + g * 4;
        _Float16* cpb = cpa + 16 * 64;
#pragma unroll
        for (int t = 0; t < 4; ++t) {
            half4v hva, hvb;
#pragma unroll
            for (int r = 0; r < 4; ++r) {
                hva[r] = (_Float16)(oa[t][r] * inva);
                hvb[r] = (_Float16)(ob[t][r] * invb);
            }
            *(half4v*)(cpa + t * 16) = hva;
            *(half4v*)(cpb + t * 16) = hvb;
        }
    }
}

// ---------------- output projection: [8192,512] @ [512,64] ----------------
// r9-proven config: 512 blocks x 64 threads (2 blocks/CU spread).
__global__ __launch_bounds__(64) void k_oproj(const _Float16* __restrict__ ctx,
                                              const _Float16* __restrict__ wo2t,
                                              const float* __restrict__ bo,
                                              float* __restrict__ out) {
    int lane = threadIdx.x & 63;
    int g = lane >> 4, c = lane & 15;
    int m0 = blockIdx.x * 16;
    int b = m0 >> 11, l = m0 & 2047;
    const _Float16* cbase = ctx + ((size_t)b * HH * LL + l) * 64;

    float4v acc[4] = {};
#pragma unroll
    for (int kc = 0; kc < 16; ++kc) {
        int hh = kc >> 1;
        const _Float16* ap = cbase + (size_t)hh * LL * 64 + c * 64 + (kc & 1) * 32 + g * 8;
        half8v a = *(const half8v*)(ap);
#pragma unroll
        for (int t = 0; t < 4; ++t) {
            half8v bf = *(const half8v*)(wo2t + (t * 16 + c) * 512 + kc * 32 + g * 8);
            acc[t] = __builtin_amdgcn_mfma_f32_16x16x32_f16(a, bf, acc[t], 0, 0, 0);
        }
    }
#pragma unroll
    for (int t = 0; t < 4; ++t) {
        float bias = bo[t * 16 + c];
#pragma unroll
        for (int r = 0; r < 4; ++r) {
            int mm = m0 + g * 4 + r;
            out[mm * 64 + t * 16 + c] = acc[t][r] + bias;
        }
    }
}

// ---------------------------------------------------------------------------
extern "C" void kernel_launch(void* const* d_in, const int* in_sizes, int n_in,
                              void* d_out, int out_size, void* d_ws, size_t ws_size,
                              hipStream_t stream) {
    const float* x  = (const float*)d_in[0];
    const float* wq = (const float*)d_in[1];
    const float* bq = (const float*)d_in[2];
    const float* wk = (const float*)d_in[3];
    const float* bk = (const float*)d_in[4];
    const float* wv = (const float*)d_in[5];
    const float* bv = (const float*)d_in[6];
    const float* wo = (const float*)d_in[7];
    const float* bo = (const float*)d_in[8];
    float* out = (float*)d_out;

    char* ws = (char*)d_ws;
    _Float16* xh    = (_Float16*)(ws);                       // 1 MB
    _Float16* wt    = (_Float16*)(ws + 1048576);             // 192 KB
    float*    biasc = (float*)   (ws + 1245184);             // 6 KB
    _Float16* wo2t  = (_Float16*)(ws + 1251328);             // 64 KB
    _Float16* qh    = (_Float16*)(ws + 1316864);             // 8 MB
    _Float16* kh    = (_Float16*)(ws + 1316864 + 1ull * 8388608);
    _Float16* vt    = (_Float16*)(ws + 1316864 + 2ull * 8388608);
    _Float16* ctx   = (_Float16*)(ws + 1316864 + 3ull * 8388608);

    hipLaunchKernelGGL(k_prep,  dim3(1024),     dim3(256), 0, stream,
                       x, wq, bq, wk, bk, wv, bv, wo, xh, wt, biasc, wo2t);
    hipLaunchKernelGGL(k_proj,  dim3(128, 24),  dim3(256), 0, stream, xh, wt, biasc, qh, kh, vt);
    hipLaunchKernelGGL(k_attn,  dim3(512),      dim3(512), 0, stream, qh, kh, vt, ctx);
    hipLaunchKernelGGL(k_oproj, dim3(512),      dim3(64),  0, stream, ctx, wo2t, bo, out);
}